// Round 5
// baseline (327.467 us; speedup 1.0000x reference)
//
#include <hip/hip_runtime.h>

#define BB 16
#define CC 80
#define HWs 16384           // H*W
#define KK 100
#define NBIN 2048           // per-batch histogram bins = okey(logit) >> 21
#define RCAP 163840         // per-batch peak-record capacity (mean ~148K, >10 sigma)
#define SCAP 2048           // per-batch survivor capacity (~500-800 expected)

// ws layout (bytes)
#define OFF_BHIST 0                         // 16*2048*4 = 131072
#define OFF_BCNT  131072                    // 16*4
#define OFF_SCNT  131136                    // 16*4
#define OFF_REC   131584                    // 16*163840*4 = 10485760
#define OFF_SURV  10617344                  // 16*2048*4 = 131072

__device__ __forceinline__ unsigned okey(float f) {
    unsigned u = __float_as_uint(f);
    return (u & 0x80000000u) ? ~u : (u | 0x80000000u);
}

// One block per 32-row band of a (b,c) plane. Streaming 3x3 stencil on raw
// logits (monotone w.r.t. sigmoid): peaks -> 4B records (bin|idx) appended
// to per-batch list + per-batch 2048-bin global histogram.
__global__ __launch_bounds__(256) void nms_kernel(const float* __restrict__ hm,
                                                  unsigned* __restrict__ rec,
                                                  int* __restrict__ bcnt,
                                                  int* __restrict__ bhist) {
    __shared__ int hist[NBIN];             // 8 KB
    const int blk = blockIdx.x;            // plane*4 + band
    const int plane = blk >> 2;
    const int band = blk & 3;
    const int b = plane / CC;
    const int c = plane - b * CC;
    const int t = threadIdx.x;
    const int lane = t & 63;
    const int sx = t & 31;                 // 4-wide column strip
    const int x0 = sx << 2;
    const int y0 = (band << 5) + ((t >> 5) << 2);   // base row of 4-row strip
    const float4* __restrict__ src4 =
        reinterpret_cast<const float4*>(hm + (size_t)plane * HWs);

    for (int i = t; i < NBIN; i += 256) hist[i] = 0;
    __syncthreads();

    // 6 independent loads (rows y0-1 .. y0+4, clamped at image boundary)
    float4 v[6];
#pragma unroll
    for (int r = 0; r < 6; ++r) {
        int rr = y0 - 1 + r;
        rr = rr < 0 ? 0 : (rr > 127 ? 127 : rr);
        v[r] = src4[(rr << 5) + sx];
    }

    auto hmax3 = [&](const float4& a) -> float4 {
        float vm1 = __shfl_up(a.w, 1, 32);
        float vp4 = __shfl_down(a.x, 1, 32);
        if (sx == 0) vm1 = a.x;            // SAME padding (self-dup neutral)
        if (sx == 31) vp4 = a.w;
        float4 h;
        h.x = fmaxf(fmaxf(vm1, a.x), a.y);
        h.y = fmaxf(fmaxf(a.x, a.y), a.z);
        h.z = fmaxf(fmaxf(a.y, a.z), a.w);
        h.w = fmaxf(fmaxf(a.z, a.w), vp4);
        return h;
    };

    unsigned pmask = 0;
    float4 hm1 = hmax3(v[0]);
    float4 h0  = hmax3(v[1]);
#pragma unroll
    for (int r = 0; r < 4; ++r) {
        float4 hp1 = hmax3(v[r + 2]);
        if (v[r + 1].x >= fmaxf(fmaxf(hm1.x, h0.x), hp1.x)) pmask |= 1u << (r * 4 + 0);
        if (v[r + 1].y >= fmaxf(fmaxf(hm1.y, h0.y), hp1.y)) pmask |= 1u << (r * 4 + 1);
        if (v[r + 1].z >= fmaxf(fmaxf(hm1.z, h0.z), hp1.z)) pmask |= 1u << (r * 4 + 2);
        if (v[r + 1].w >= fmaxf(fmaxf(hm1.w, h0.w), hp1.w)) pmask |= 1u << (r * 4 + 3);
        hm1 = h0; h0 = hp1;
    }

    // wave-level compaction: one global atomic per wave
    int cntp = __popc(pmask);
    int sc = cntp;
#pragma unroll
    for (int off = 1; off < 64; off <<= 1) {
        int n = __shfl_up(sc, off, 64);
        if (lane >= off) sc += n;
    }
    int total = __shfl(sc, 63, 64);
    int basew = 0;
    if (lane == 63 && total > 0) basew = atomicAdd(&bcnt[b], total);
    basew = __shfl(basew, 63, 64);
    int w = basew + sc - cntp;             // exclusive offset

    unsigned* __restrict__ rb = rec + (size_t)b * RCAP;
#pragma unroll
    for (int r = 0; r < 4; ++r) {
        float vv0 = v[r + 1].x, vv1 = v[r + 1].y, vv2 = v[r + 1].z, vv3 = v[r + 1].w;
#pragma unroll
        for (int j = 0; j < 4; ++j) {
            if (pmask & (1u << (r * 4 + j))) {
                float lv = (j == 0) ? vv0 : (j == 1) ? vv1 : (j == 2) ? vv2 : vv3;
                unsigned bin = okey(lv) >> 21;
                atomicAdd(&hist[bin], 1);
                unsigned idx = ((unsigned)c << 14) | ((unsigned)(y0 + r) << 7)
                             | (unsigned)(x0 + j);
                if (w < RCAP) rb[w] = (bin << 21) | idx;
                ++w;
            }
        }
    }

    __syncthreads();
    for (int i = t; i < NBIN; i += 256) {
        int hv = hist[i];
        if (hv) atomicAdd(&bhist[b * NBIN + i], hv);
    }
}

// 8 blocks per batch: recompute batch cutoff bin (largest bin with suffix
// count >= K -> provable superset of the top-100 incl. sigmoid tie groups),
// filter record slice, emit survivor indices.
__global__ __launch_bounds__(256) void filter_kernel(const unsigned* __restrict__ rec,
                                                     const int* __restrict__ bcnt,
                                                     const int* __restrict__ bhist,
                                                     unsigned* __restrict__ surv,
                                                     int* __restrict__ scnt) {
    __shared__ int csum[256];
    __shared__ int s_cut;
    const int b = blockIdx.x >> 3;
    const int slice = blockIdx.x & 7;
    const int t = threadIdx.x;

    int h[8]; int chunk = 0;
#pragma unroll
    for (int j = 0; j < 8; ++j) {
        h[j] = bhist[b * NBIN + (t << 3) + j];
        chunk += h[j];
    }
    csum[t] = chunk;
    if (t == 0) s_cut = 0;
    __syncthreads();
    for (int off = 1; off < 256; off <<= 1) {
        int v = (t + off < 256) ? csum[t + off] : 0;
        __syncthreads();
        csum[t] += v;
        __syncthreads();
    }
    if (csum[0] > KK) {
        int running = (t < 255) ? csum[t + 1] : 0;
        if (csum[t] >= KK && running < KK) {   // exactly one thread
            for (int j = 7; j >= 0; --j) {
                running += h[j];
                if (running >= KK) { s_cut = (t << 3) + j; break; }
            }
        }
    }
    __syncthreads();
    const unsigned cut = (unsigned)s_cut;

    int Nc = bcnt[b]; if (Nc > RCAP) Nc = RCAP;
    int per = (Nc + 7) >> 3;
    int lo = slice * per;
    int hi = lo + per; if (hi > Nc) hi = Nc;
    const unsigned* __restrict__ rb = rec + (size_t)b * RCAP;
    for (int i = lo + t; i < hi; i += 256) {
        unsigned rv = rb[i];
        if ((rv >> 21) >= cut) {
            int slot = atomicAdd(&scnt[b], 1);
            if (slot < SCAP) surv[b * SCAP + slot] = rv & 0x1FFFFFu;
        }
    }
}

// One block per batch: gather exact logits for survivors, sigmoid, sort by
// (sigmoid_bits desc, idx asc) == lax.top_k tie semantics, gather + emit.
__global__ __launch_bounds__(256) void topk_kernel(const unsigned* __restrict__ surv,
                                                   const int* __restrict__ scnt,
                                                   const float* __restrict__ hm,
                                                   const float* __restrict__ bbox,
                                                   const float* __restrict__ offs,
                                                   const int* __restrict__ image_id,
                                                   float* __restrict__ out) {
    __shared__ unsigned long long list[SCAP];  // 16 KB
    const int b = blockIdx.x;
    const int t = threadIdx.x;
    int n = scnt[b]; if (n > SCAP) n = SCAP;
    const float* __restrict__ hb = hm + (size_t)b * CC * HWs;

    for (int i = t; i < n; i += 256) {
        unsigned idx = surv[b * SCAP + i];
        float lv = hb[idx];
        float s = 1.0f / (1.0f + expf(-lv));
        list[i] = ((unsigned long long)__float_as_uint(s) << 32) | (unsigned)(~idx);
    }
    int P = 128;
    while (P < n) P <<= 1;
    for (int i = n + t; i < P; i += 256) list[i] = 0ull;
    __syncthreads();

    for (int ksz = 2; ksz <= P; ksz <<= 1) {
        for (int j = ksz >> 1; j > 0; j >>= 1) {
            for (int i = t; i < P; i += 256) {
                int ixj = i ^ j;
                if (ixj > i) {
                    unsigned long long a = list[i], bb2 = list[ixj];
                    bool desc = ((i & ksz) == 0);
                    if (desc ? (a < bb2) : (a > bb2)) { list[i] = bb2; list[ixj] = a; }
                }
            }
            __syncthreads();
        }
    }

    if (t < KK) {
        float s = 0.0f; unsigned idx = 0;
        if (t < n) {
            unsigned long long cv = list[t];
            s = __uint_as_float((unsigned)(cv >> 32));
            idx = ~(unsigned)(cv & 0xFFFFFFFFu) & 0x1FFFFFu;
        }
        unsigned sp = idx & (HWs - 1);
        float cls = (float)(idx >> 14);
        float ysf = (float)(sp >> 7);
        float xsf = (float)(sp & 127);
        const float* __restrict__ ob  = offs + (size_t)b * 2 * HWs;
        const float* __restrict__ bbx = bbox + (size_t)b * 2 * HWs;
        float cx = xsf + ob[sp];
        float cy = ysf + ob[HWs + sp];
        float w = bbx[sp];
        float h = bbx[HWs + sp];
        float* row = out + ((size_t)b * KK + t) * 7;
        row[0] = (float)image_id[b];
        row[1] = (cx - w * 0.5f) * 4.0f;
        row[2] = (cy - h * 0.5f) * 4.0f;
        row[3] = (cx + w * 0.5f) * 4.0f;
        row[4] = (cy + h * 0.5f) * 4.0f;
        row[5] = s;
        row[6] = cls;
    }
}

extern "C" void kernel_launch(void* const* d_in, const int* in_sizes, int n_in,
                              void* d_out, int out_size, void* d_ws, size_t ws_size,
                              hipStream_t stream) {
    const float* hm      = (const float*)d_in[0];
    const float* bbox    = (const float*)d_in[1];
    const float* offset  = (const float*)d_in[2];
    const int*   img_id  = (const int*)d_in[3];
    float* out = (float*)d_out;

    char* ws = (char*)d_ws;
    int*      bhist = (int*)(ws + OFF_BHIST);
    int*      bcnt  = (int*)(ws + OFF_BCNT);
    int*      scnt  = (int*)(ws + OFF_SCNT);
    unsigned* rec   = (unsigned*)(ws + OFF_REC);
    unsigned* surv  = (unsigned*)(ws + OFF_SURV);

    hipMemsetAsync(d_ws, 0, 131200, stream);   // bhist + bcnt + scnt
    nms_kernel<<<BB * CC * 4, 256, 0, stream>>>(hm, rec, bcnt, bhist);
    filter_kernel<<<BB * 8, 256, 0, stream>>>(rec, bcnt, bhist, surv, scnt);
    topk_kernel<<<BB, 256, 0, stream>>>(surv, scnt, hm, bbox, offset, img_id, out);
}

// Round 6
// 65.872 us; speedup vs baseline: 4.9713x; 4.9713x over previous
//
#include <hip/hip_runtime.h>

#define BB 16
#define CC 80
#define HWs 16384           // H*W
#define KK 100
#define NBIN 2048           // histogram bins = okey(logit) >> 21
#define NSLOT 320           // band slots per batch = CC*4
#define BCAP 576            // records per band slot (mean 455, ~6 sigma)
#define SBCAP 32            // survivors per band slot (mean ~2)

// ws layout (bytes)
#define OFF_BHIST 0                          // 16*2048*4 = 131072
#define OFF_CUT   131072                     // 16*4
#define OFF_PBCNT 131136                     // 5120*4 = 20480
#define OFF_PSCNT 151616                     // 5120*4 = 20480
#define OFF_REC   172096                     // 16*320*576*4 = 11796480
#define OFF_SURV  11968576                   // 16*320*32*4  = 655360  (end ~12.6MB)

__device__ __forceinline__ unsigned okey(float f) {
    unsigned u = __float_as_uint(f);
    return (u & 0x80000000u) ? ~u : (u | 0x80000000u);
}

// One block per 32-row band of a (b,c) plane. Streaming 3x3 stencil on raw
// logits (monotone w.r.t. sigmoid). Records -> block-owned slot (NO returning
// global atomics). Histogram flushed with fire-and-forget atomics.
__global__ __launch_bounds__(256) void nms_kernel(const float* __restrict__ hm,
                                                  unsigned* __restrict__ rec,
                                                  int* __restrict__ pbcnt,
                                                  int* __restrict__ bhist) {
    __shared__ int hist[NBIN];             // 8 KB
    __shared__ int wbase[4];
    const int blk = blockIdx.x;            // plane*4 + band
    const int plane = blk >> 2;
    const int band = blk & 3;
    const int b = plane / CC;
    const int c = plane - b * CC;
    const int slot = (c << 2) | band;      // band slot within batch
    const int t = threadIdx.x;
    const int lane = t & 63;
    const int wid = t >> 6;
    const int sx = t & 31;                 // 4-wide column strip
    const int x0 = sx << 2;
    const int y0 = (band << 5) + ((t >> 5) << 2);   // base row of 4-row strip
    const float4* __restrict__ src4 =
        reinterpret_cast<const float4*>(hm + (size_t)plane * HWs);

    for (int i = t; i < NBIN; i += 256) hist[i] = 0;
    __syncthreads();

    // 6 independent loads (rows y0-1 .. y0+4, clamped at image boundary)
    float4 v[6];
#pragma unroll
    for (int r = 0; r < 6; ++r) {
        int rr = y0 - 1 + r;
        rr = rr < 0 ? 0 : (rr > 127 ? 127 : rr);
        v[r] = src4[(rr << 5) + sx];
    }

    auto hmax3 = [&](const float4& a) -> float4 {
        float vm1 = __shfl_up(a.w, 1, 32);
        float vp4 = __shfl_down(a.x, 1, 32);
        if (sx == 0) vm1 = a.x;            // SAME padding (self-dup neutral)
        if (sx == 31) vp4 = a.w;
        float4 h;
        h.x = fmaxf(fmaxf(vm1, a.x), a.y);
        h.y = fmaxf(fmaxf(a.x, a.y), a.z);
        h.z = fmaxf(fmaxf(a.y, a.z), a.w);
        h.w = fmaxf(fmaxf(a.z, a.w), vp4);
        return h;
    };

    unsigned pmask = 0;
    float4 hm1 = hmax3(v[0]);
    float4 h0  = hmax3(v[1]);
#pragma unroll
    for (int r = 0; r < 4; ++r) {
        float4 hp1 = hmax3(v[r + 2]);
        if (v[r + 1].x >= fmaxf(fmaxf(hm1.x, h0.x), hp1.x)) pmask |= 1u << (r * 4 + 0);
        if (v[r + 1].y >= fmaxf(fmaxf(hm1.y, h0.y), hp1.y)) pmask |= 1u << (r * 4 + 1);
        if (v[r + 1].z >= fmaxf(fmaxf(hm1.z, h0.z), hp1.z)) pmask |= 1u << (r * 4 + 2);
        if (v[r + 1].w >= fmaxf(fmaxf(hm1.w, h0.w), hp1.w)) pmask |= 1u << (r * 4 + 3);
        hm1 = h0; h0 = hp1;
    }

    // wave inclusive scan of per-thread peak counts
    int cntp = __popc(pmask);
    int sc = cntp;
#pragma unroll
    for (int off = 1; off < 64; off <<= 1) {
        int n = __shfl_up(sc, off, 64);
        if (lane >= off) sc += n;
    }
    if (lane == 63) wbase[wid] = sc;       // wave totals
    __syncthreads();
    int wexcl = 0;
#pragma unroll
    for (int i = 0; i < 4; ++i) if (i < wid) wexcl += wbase[i];
    int w = wexcl + sc - cntp;             // deterministic offset in block slot

    unsigned* __restrict__ rb = rec + ((size_t)b * NSLOT + slot) * BCAP;
#pragma unroll
    for (int r = 0; r < 4; ++r) {
        float vv0 = v[r + 1].x, vv1 = v[r + 1].y, vv2 = v[r + 1].z, vv3 = v[r + 1].w;
#pragma unroll
        for (int j = 0; j < 4; ++j) {
            if (pmask & (1u << (r * 4 + j))) {
                float lv = (j == 0) ? vv0 : (j == 1) ? vv1 : (j == 2) ? vv2 : vv3;
                unsigned bin = okey(lv) >> 21;
                atomicAdd(&hist[bin], 1);
                unsigned idx = ((unsigned)c << 14) | ((unsigned)(y0 + r) << 7)
                             | (unsigned)(x0 + j);
                if (w < BCAP) rb[w] = (bin << 21) | idx;
                ++w;
            }
        }
    }
    if (t == 0) {
        int tot = wbase[0] + wbase[1] + wbase[2] + wbase[3];
        pbcnt[b * NSLOT + slot] = tot > BCAP ? BCAP : tot;
    }

    __syncthreads();
    for (int i = t; i < NBIN; i += 256) {
        int hv = hist[i];
        if (hv) atomicAdd(&bhist[b * NBIN + i], hv);   // fire-and-forget
    }
}

// One block per batch: cutoff = largest bin with suffix count >= K
// (superset of the exact sigmoid-top-100 incl. tie groups).
__global__ __launch_bounds__(256) void cut_kernel(const int* __restrict__ bhist,
                                                  int* __restrict__ cut) {
    __shared__ int csum[256];
    __shared__ int s_cut;
    const int b = blockIdx.x;
    const int t = threadIdx.x;

    int h[8]; int chunk = 0;
#pragma unroll
    for (int j = 0; j < 8; ++j) {
        h[j] = bhist[b * NBIN + (t << 3) + j];
        chunk += h[j];
    }
    csum[t] = chunk;
    if (t == 0) s_cut = 0;
    __syncthreads();
    for (int off = 1; off < 256; off <<= 1) {
        int v = (t + off < 256) ? csum[t + off] : 0;
        __syncthreads();
        csum[t] += v;
        __syncthreads();
    }
    if (csum[0] > KK) {
        int running = (t < 255) ? csum[t + 1] : 0;
        if (csum[t] >= KK && running < KK) {   // exactly one thread
            for (int j = 7; j >= 0; --j) {
                running += h[j];
                if (running >= KK) { s_cut = (t << 3) + j; break; }
            }
        }
    }
    __syncthreads();
    if (t == 0) cut[b] = s_cut;
}

// One block per band slot: filter records against cut[b] -> deterministic
// survivor slot (LDS-atomic compaction only).
__global__ __launch_bounds__(256) void filter_kernel(const unsigned* __restrict__ rec,
                                                     const int* __restrict__ pbcnt,
                                                     const int* __restrict__ cut,
                                                     unsigned* __restrict__ surv,
                                                     int* __restrict__ pscnt) {
    __shared__ int s_n;
    const int bx = blockIdx.x;             // b*NSLOT + slot
    const int b = bx / NSLOT;
    const int t = threadIdx.x;
    if (t == 0) s_n = 0;
    __syncthreads();

    int n = pbcnt[bx]; if (n > BCAP) n = BCAP;
    const int cutb = cut[b];
    const unsigned* __restrict__ rb = rec + (size_t)bx * BCAP;
    unsigned* __restrict__ sb = surv + (size_t)bx * SBCAP;
    for (int i = t; i < n; i += 256) {
        unsigned rv = rb[i];
        if ((int)(rv >> 21) >= cutb) {
            int sl = atomicAdd(&s_n, 1);   // LDS atomic: cheap
            if (sl < SBCAP) sb[sl] = rv & 0x1FFFFFu;
        }
    }
    __syncthreads();
    if (t == 0) pscnt[bx] = s_n > SBCAP ? SBCAP : s_n;
}

// One block per batch: gather survivors, exact logit -> sigmoid, sort by
// (sigmoid_bits desc, idx asc) == lax.top_k tie semantics, gather + emit.
__global__ __launch_bounds__(256) void topk_kernel(const unsigned* __restrict__ surv,
                                                   const int* __restrict__ pscnt,
                                                   const float* __restrict__ hm,
                                                   const float* __restrict__ bbox,
                                                   const float* __restrict__ offs,
                                                   const int* __restrict__ image_id,
                                                   float* __restrict__ out) {
    __shared__ int lcnt[NSLOT];
    __shared__ unsigned uidx[2048];            // 8 KB
    __shared__ unsigned long long list[2048];  // 16 KB
    __shared__ int s_n;
    const int b = blockIdx.x;
    const int t = threadIdx.x;
    const float* __restrict__ hb = hm + (size_t)b * CC * HWs;

    for (int s = t; s < NSLOT; s += 256) lcnt[s] = pscnt[b * NSLOT + s];
    if (t == 0) s_n = 0;
    __syncthreads();

    for (int s = t; s < NSLOT; s += 256) {
        int cs = lcnt[s]; if (cs > SBCAP) cs = SBCAP;
        if (cs) {
            int base = atomicAdd(&s_n, cs);
            const unsigned* __restrict__ sb = surv + ((size_t)b * NSLOT + s) * SBCAP;
            for (int k = 0; k < cs; ++k)
                if (base + k < 2048) uidx[base + k] = sb[k];
        }
    }
    __syncthreads();
    int n = s_n; if (n > 2048) n = 2048;

    for (int i = t; i < n; i += 256) {
        unsigned idx = uidx[i];
        float lv = hb[idx];
        float s = 1.0f / (1.0f + expf(-lv));
        list[i] = ((unsigned long long)__float_as_uint(s) << 32) | (unsigned)(~idx);
    }
    int P = 128;
    while (P < n) P <<= 1;
    for (int i = n + t; i < P; i += 256) list[i] = 0ull;
    __syncthreads();

    for (int ksz = 2; ksz <= P; ksz <<= 1) {
        for (int j = ksz >> 1; j > 0; j >>= 1) {
            for (int i = t; i < P; i += 256) {
                int ixj = i ^ j;
                if (ixj > i) {
                    unsigned long long a = list[i], bb2 = list[ixj];
                    bool desc = ((i & ksz) == 0);
                    if (desc ? (a < bb2) : (a > bb2)) { list[i] = bb2; list[ixj] = a; }
                }
            }
            __syncthreads();
        }
    }

    if (t < KK) {
        float s = 0.0f; unsigned idx = 0;
        if (t < n) {
            unsigned long long cv = list[t];
            s = __uint_as_float((unsigned)(cv >> 32));
            idx = ~(unsigned)(cv & 0xFFFFFFFFu) & 0x1FFFFFu;
        }
        unsigned sp = idx & (HWs - 1);
        float cls = (float)(idx >> 14);
        float ysf = (float)(sp >> 7);
        float xsf = (float)(sp & 127);
        const float* __restrict__ ob  = offs + (size_t)b * 2 * HWs;
        const float* __restrict__ bbx = bbox + (size_t)b * 2 * HWs;
        float cx = xsf + ob[sp];
        float cy = ysf + ob[HWs + sp];
        float w = bbx[sp];
        float h = bbx[HWs + sp];
        float* row = out + ((size_t)b * KK + t) * 7;
        row[0] = (float)image_id[b];
        row[1] = (cx - w * 0.5f) * 4.0f;
        row[2] = (cy - h * 0.5f) * 4.0f;
        row[3] = (cx + w * 0.5f) * 4.0f;
        row[4] = (cy + h * 0.5f) * 4.0f;
        row[5] = s;
        row[6] = cls;
    }
}

extern "C" void kernel_launch(void* const* d_in, const int* in_sizes, int n_in,
                              void* d_out, int out_size, void* d_ws, size_t ws_size,
                              hipStream_t stream) {
    const float* hm      = (const float*)d_in[0];
    const float* bbox    = (const float*)d_in[1];
    const float* offset  = (const float*)d_in[2];
    const int*   img_id  = (const int*)d_in[3];
    float* out = (float*)d_out;

    char* ws = (char*)d_ws;
    int*      bhist = (int*)(ws + OFF_BHIST);
    int*      cut   = (int*)(ws + OFF_CUT);
    int*      pbcnt = (int*)(ws + OFF_PBCNT);
    int*      pscnt = (int*)(ws + OFF_PSCNT);
    unsigned* rec   = (unsigned*)(ws + OFF_REC);
    unsigned* surv  = (unsigned*)(ws + OFF_SURV);

    hipMemsetAsync(bhist, 0, BB * NBIN * 4, stream);   // histogram only
    nms_kernel<<<BB * CC * 4, 256, 0, stream>>>(hm, rec, pbcnt, bhist);
    cut_kernel<<<BB, 256, 0, stream>>>(bhist, cut);
    filter_kernel<<<BB * NSLOT, 256, 0, stream>>>(rec, pbcnt, cut, surv, pscnt);
    topk_kernel<<<BB, 256, 0, stream>>>(surv, pscnt, hm, bbox, offset, img_id, out);
}

// Round 7
// 65.448 us; speedup vs baseline: 5.0035x; 1.0065x over previous
//
#include <hip/hip_runtime.h>

#define BB 16
#define CC 80
#define HWs 16384           // H*W
#define KK 100
#define NBIN 2048           // histogram bins = okey(logit) >> 21
#define NSLOT 320           // band slots per batch = CC*4
#define BCAP 576            // records per band slot (mean 455, ~6 sigma)
#define SBCAP 32            // survivors per band slot (mean ~2)

// ws layout (bytes)
#define OFF_BHIST 0                          // 16*2048*4 = 131072
#define OFF_CUT   131072                     // 16*4
#define OFF_PBCNT 131136                     // 5120*4 = 20480
#define OFF_PSCNT 151616                     // 5120*4 = 20480
#define OFF_REC   172096                     // 16*320*576*4 = 11796480
#define OFF_SURV  11968576                   // 16*320*32*4  = 655360  (end ~12.6MB)

__device__ __forceinline__ unsigned okey(float f) {
    unsigned u = __float_as_uint(f);
    return (u & 0x80000000u) ? ~u : (u | 0x80000000u);
}

// 32 blocks x 256 threads, int4 stores: zero the 128 KB batch histogram.
// (hipMemsetAsync ran as a ~50us serial fillBuffer inside the graph.)
__global__ __launch_bounds__(256) void zero_hist_kernel(int4* __restrict__ bhist) {
    int i = blockIdx.x * 256 + threadIdx.x;          // 8192 int4 total
    if (i < BB * NBIN / 4) bhist[i] = make_int4(0, 0, 0, 0);
}

// One block per 32-row band of a (b,c) plane. Streaming 3x3 stencil on raw
// logits (monotone w.r.t. sigmoid). Records -> block-owned slot (NO returning
// global atomics). Histogram flushed with fire-and-forget atomics.
__global__ __launch_bounds__(256) void nms_kernel(const float* __restrict__ hm,
                                                  unsigned* __restrict__ rec,
                                                  int* __restrict__ pbcnt,
                                                  int* __restrict__ bhist) {
    __shared__ int hist[NBIN];             // 8 KB
    __shared__ int wbase[4];
    const int blk = blockIdx.x;            // plane*4 + band
    const int plane = blk >> 2;
    const int band = blk & 3;
    const int b = plane / CC;
    const int c = plane - b * CC;
    const int slot = (c << 2) | band;      // band slot within batch
    const int t = threadIdx.x;
    const int lane = t & 63;
    const int wid = t >> 6;
    const int sx = t & 31;                 // 4-wide column strip
    const int x0 = sx << 2;
    const int y0 = (band << 5) + ((t >> 5) << 2);   // base row of 4-row strip
    const float4* __restrict__ src4 =
        reinterpret_cast<const float4*>(hm + (size_t)plane * HWs);

    for (int i = t; i < NBIN; i += 256) hist[i] = 0;
    __syncthreads();

    // 6 independent loads (rows y0-1 .. y0+4, clamped at image boundary)
    float4 v[6];
#pragma unroll
    for (int r = 0; r < 6; ++r) {
        int rr = y0 - 1 + r;
        rr = rr < 0 ? 0 : (rr > 127 ? 127 : rr);
        v[r] = src4[(rr << 5) + sx];
    }

    auto hmax3 = [&](const float4& a) -> float4 {
        float vm1 = __shfl_up(a.w, 1, 32);
        float vp4 = __shfl_down(a.x, 1, 32);
        if (sx == 0) vm1 = a.x;            // SAME padding (self-dup neutral)
        if (sx == 31) vp4 = a.w;
        float4 h;
        h.x = fmaxf(fmaxf(vm1, a.x), a.y);
        h.y = fmaxf(fmaxf(a.x, a.y), a.z);
        h.z = fmaxf(fmaxf(a.y, a.z), a.w);
        h.w = fmaxf(fmaxf(a.z, a.w), vp4);
        return h;
    };

    unsigned pmask = 0;
    float4 hm1 = hmax3(v[0]);
    float4 h0  = hmax3(v[1]);
#pragma unroll
    for (int r = 0; r < 4; ++r) {
        float4 hp1 = hmax3(v[r + 2]);
        if (v[r + 1].x >= fmaxf(fmaxf(hm1.x, h0.x), hp1.x)) pmask |= 1u << (r * 4 + 0);
        if (v[r + 1].y >= fmaxf(fmaxf(hm1.y, h0.y), hp1.y)) pmask |= 1u << (r * 4 + 1);
        if (v[r + 1].z >= fmaxf(fmaxf(hm1.z, h0.z), hp1.z)) pmask |= 1u << (r * 4 + 2);
        if (v[r + 1].w >= fmaxf(fmaxf(hm1.w, h0.w), hp1.w)) pmask |= 1u << (r * 4 + 3);
        hm1 = h0; h0 = hp1;
    }

    // wave inclusive scan of per-thread peak counts
    int cntp = __popc(pmask);
    int sc = cntp;
#pragma unroll
    for (int off = 1; off < 64; off <<= 1) {
        int n = __shfl_up(sc, off, 64);
        if (lane >= off) sc += n;
    }
    if (lane == 63) wbase[wid] = sc;       // wave totals
    __syncthreads();
    int wexcl = 0;
#pragma unroll
    for (int i = 0; i < 4; ++i) if (i < wid) wexcl += wbase[i];
    int w = wexcl + sc - cntp;             // deterministic offset in block slot

    unsigned* __restrict__ rb = rec + ((size_t)b * NSLOT + slot) * BCAP;
#pragma unroll
    for (int r = 0; r < 4; ++r) {
        float vv0 = v[r + 1].x, vv1 = v[r + 1].y, vv2 = v[r + 1].z, vv3 = v[r + 1].w;
#pragma unroll
        for (int j = 0; j < 4; ++j) {
            if (pmask & (1u << (r * 4 + j))) {
                float lv = (j == 0) ? vv0 : (j == 1) ? vv1 : (j == 2) ? vv2 : vv3;
                unsigned bin = okey(lv) >> 21;
                atomicAdd(&hist[bin], 1);
                unsigned idx = ((unsigned)c << 14) | ((unsigned)(y0 + r) << 7)
                             | (unsigned)(x0 + j);
                if (w < BCAP) rb[w] = (bin << 21) | idx;
                ++w;
            }
        }
    }
    if (t == 0) {
        int tot = wbase[0] + wbase[1] + wbase[2] + wbase[3];
        pbcnt[b * NSLOT + slot] = tot > BCAP ? BCAP : tot;
    }

    __syncthreads();
    for (int i = t; i < NBIN; i += 256) {
        int hv = hist[i];
        if (hv) atomicAdd(&bhist[b * NBIN + i], hv);   // fire-and-forget
    }
}

// One block per batch: cutoff = largest bin with suffix count >= K
// (superset of the exact sigmoid-top-100 incl. tie groups).
__global__ __launch_bounds__(256) void cut_kernel(const int* __restrict__ bhist,
                                                  int* __restrict__ cut) {
    __shared__ int csum[256];
    __shared__ int s_cut;
    const int b = blockIdx.x;
    const int t = threadIdx.x;

    int h[8]; int chunk = 0;
#pragma unroll
    for (int j = 0; j < 8; ++j) {
        h[j] = bhist[b * NBIN + (t << 3) + j];
        chunk += h[j];
    }
    csum[t] = chunk;
    if (t == 0) s_cut = 0;
    __syncthreads();
    for (int off = 1; off < 256; off <<= 1) {
        int v = (t + off < 256) ? csum[t + off] : 0;
        __syncthreads();
        csum[t] += v;
        __syncthreads();
    }
    if (csum[0] > KK) {
        int running = (t < 255) ? csum[t + 1] : 0;
        if (csum[t] >= KK && running < KK) {   // exactly one thread
            for (int j = 7; j >= 0; --j) {
                running += h[j];
                if (running >= KK) { s_cut = (t << 3) + j; break; }
            }
        }
    }
    __syncthreads();
    if (t == 0) cut[b] = s_cut;
}

// One block per band slot: filter records against cut[b] -> deterministic
// survivor slot (LDS-atomic compaction only).
__global__ __launch_bounds__(256) void filter_kernel(const unsigned* __restrict__ rec,
                                                     const int* __restrict__ pbcnt,
                                                     const int* __restrict__ cut,
                                                     unsigned* __restrict__ surv,
                                                     int* __restrict__ pscnt) {
    __shared__ int s_n;
    const int bx = blockIdx.x;             // b*NSLOT + slot
    const int b = bx / NSLOT;
    const int t = threadIdx.x;
    if (t == 0) s_n = 0;
    __syncthreads();

    int n = pbcnt[bx]; if (n > BCAP) n = BCAP;
    const int cutb = cut[b];
    const unsigned* __restrict__ rb = rec + (size_t)bx * BCAP;
    unsigned* __restrict__ sb = surv + (size_t)bx * SBCAP;
    for (int i = t; i < n; i += 256) {
        unsigned rv = rb[i];
        if ((int)(rv >> 21) >= cutb) {
            int sl = atomicAdd(&s_n, 1);   // LDS atomic: cheap
            if (sl < SBCAP) sb[sl] = rv & 0x1FFFFFu;
        }
    }
    __syncthreads();
    if (t == 0) pscnt[bx] = s_n > SBCAP ? SBCAP : s_n;
}

// One block per batch: gather survivors, exact logit -> sigmoid, sort by
// (sigmoid_bits desc, idx asc) == lax.top_k tie semantics, gather + emit.
__global__ __launch_bounds__(256) void topk_kernel(const unsigned* __restrict__ surv,
                                                   const int* __restrict__ pscnt,
                                                   const float* __restrict__ hm,
                                                   const float* __restrict__ bbox,
                                                   const float* __restrict__ offs,
                                                   const int* __restrict__ image_id,
                                                   float* __restrict__ out) {
    __shared__ int lcnt[NSLOT];
    __shared__ unsigned uidx[2048];            // 8 KB
    __shared__ unsigned long long list[2048];  // 16 KB
    __shared__ int s_n;
    const int b = blockIdx.x;
    const int t = threadIdx.x;
    const float* __restrict__ hb = hm + (size_t)b * CC * HWs;

    for (int s = t; s < NSLOT; s += 256) lcnt[s] = pscnt[b * NSLOT + s];
    if (t == 0) s_n = 0;
    __syncthreads();

    for (int s = t; s < NSLOT; s += 256) {
        int cs = lcnt[s]; if (cs > SBCAP) cs = SBCAP;
        if (cs) {
            int base = atomicAdd(&s_n, cs);
            const unsigned* __restrict__ sb = surv + ((size_t)b * NSLOT + s) * SBCAP;
            for (int k = 0; k < cs; ++k)
                if (base + k < 2048) uidx[base + k] = sb[k];
        }
    }
    __syncthreads();
    int n = s_n; if (n > 2048) n = 2048;

    for (int i = t; i < n; i += 256) {
        unsigned idx = uidx[i];
        float lv = hb[idx];
        float s = 1.0f / (1.0f + expf(-lv));
        list[i] = ((unsigned long long)__float_as_uint(s) << 32) | (unsigned)(~idx);
    }
    int P = 128;
    while (P < n) P <<= 1;
    for (int i = n + t; i < P; i += 256) list[i] = 0ull;
    __syncthreads();

    for (int ksz = 2; ksz <= P; ksz <<= 1) {
        for (int j = ksz >> 1; j > 0; j >>= 1) {
            for (int i = t; i < P; i += 256) {
                int ixj = i ^ j;
                if (ixj > i) {
                    unsigned long long a = list[i], bb2 = list[ixj];
                    bool desc = ((i & ksz) == 0);
                    if (desc ? (a < bb2) : (a > bb2)) { list[i] = bb2; list[ixj] = a; }
                }
            }
            __syncthreads();
        }
    }

    if (t < KK) {
        float s = 0.0f; unsigned idx = 0;
        if (t < n) {
            unsigned long long cv = list[t];
            s = __uint_as_float((unsigned)(cv >> 32));
            idx = ~(unsigned)(cv & 0xFFFFFFFFu) & 0x1FFFFFu;
        }
        unsigned sp = idx & (HWs - 1);
        float cls = (float)(idx >> 14);
        float ysf = (float)(sp >> 7);
        float xsf = (float)(sp & 127);
        const float* __restrict__ ob  = offs + (size_t)b * 2 * HWs;
        const float* __restrict__ bbx = bbox + (size_t)b * 2 * HWs;
        float cx = xsf + ob[sp];
        float cy = ysf + ob[HWs + sp];
        float w = bbx[sp];
        float h = bbx[HWs + sp];
        float* row = out + ((size_t)b * KK + t) * 7;
        row[0] = (float)image_id[b];
        row[1] = (cx - w * 0.5f) * 4.0f;
        row[2] = (cy - h * 0.5f) * 4.0f;
        row[3] = (cx + w * 0.5f) * 4.0f;
        row[4] = (cy + h * 0.5f) * 4.0f;
        row[5] = s;
        row[6] = cls;
    }
}

extern "C" void kernel_launch(void* const* d_in, const int* in_sizes, int n_in,
                              void* d_out, int out_size, void* d_ws, size_t ws_size,
                              hipStream_t stream) {
    const float* hm      = (const float*)d_in[0];
    const float* bbox    = (const float*)d_in[1];
    const float* offset  = (const float*)d_in[2];
    const int*   img_id  = (const int*)d_in[3];
    float* out = (float*)d_out;

    char* ws = (char*)d_ws;
    int*      bhist = (int*)(ws + OFF_BHIST);
    int*      cut   = (int*)(ws + OFF_CUT);
    int*      pbcnt = (int*)(ws + OFF_PBCNT);
    int*      pscnt = (int*)(ws + OFF_PSCNT);
    unsigned* rec   = (unsigned*)(ws + OFF_REC);
    unsigned* surv  = (unsigned*)(ws + OFF_SURV);

    zero_hist_kernel<<<32, 256, 0, stream>>>((int4*)bhist);
    nms_kernel<<<BB * CC * 4, 256, 0, stream>>>(hm, rec, pbcnt, bhist);
    cut_kernel<<<BB, 256, 0, stream>>>(bhist, cut);
    filter_kernel<<<BB * NSLOT, 256, 0, stream>>>(rec, pbcnt, cut, surv, pscnt);
    topk_kernel<<<BB, 256, 0, stream>>>(surv, pscnt, hm, bbox, offset, img_id, out);
}

// Round 8
// 62.332 us; speedup vs baseline: 5.2536x; 1.0500x over previous
//
#include <hip/hip_runtime.h>

#define BB 16
#define CC 80
#define HWs 16384           // H*W
#define KK 100
#define NBIN 2048           // histogram bins = okey(logit) >> 21
#define BCAP 2304           // records per plane slot (mean ~1820, big margin)
#define SBCAP 128           // survivors per plane slot (mean ~8)

// ws layout (bytes)
#define OFF_BHIST 0                          // 16*2048*4 = 131072
#define OFF_CUT   131072                     // 64
#define OFF_PBCNT 131136                     // 1280*4 = 5120
#define OFF_PSCNT 136256                     // 1280*4 = 5120
#define OFF_REC   141376                     // 16*80*2304*4 = 11796480
#define OFF_SURV  11937856                   // 16*80*128*4 = 655360 (end ~12.6MB)

__device__ __forceinline__ unsigned okey(float f) {
    unsigned u = __float_as_uint(f);
    return (u & 0x80000000u) ? ~u : (u | 0x80000000u);
}

// 32 blocks x 256 threads: zero the 128 KB batch histogram.
__global__ __launch_bounds__(256) void zero_hist_kernel(int4* __restrict__ bhist) {
    int i = blockIdx.x * 256 + threadIdx.x;          // 8192 int4 total
    if (i < BB * NBIN / 4) bhist[i] = make_int4(0, 0, 0, 0);
}

// One block per (b,c) plane (1280 blocks). 256 threads = 32 col-strips x 8
// bands of 16 rows; 4 chunks of 4 rows each. Streaming 3x3 stencil on raw
// logits (monotone w.r.t. sigmoid). Records -> plane-owned slot with
// deterministic offsets (no returning global atomics). LDS hist zeroed and
// flushed ONCE per plane (4x amortized vs band-per-block).
__global__ __launch_bounds__(256) void nms_kernel(const float* __restrict__ hm,
                                                  unsigned* __restrict__ rec,
                                                  int* __restrict__ pbcnt,
                                                  int* __restrict__ bhist) {
    __shared__ int hist[NBIN];             // 8 KB
    __shared__ int wbase[4];
    const int plane = blockIdx.x;          // b*CC + c
    const int b = plane / CC;
    const int c = plane - b * CC;
    const int t = threadIdx.x;
    const int lane = t & 63;
    const int wid = t >> 6;
    const int sx = t & 31;                 // 4-wide column strip
    const int x0 = sx << 2;
    const int band0 = (t >> 5) << 4;       // 8 bands x 16 rows
    const float4* __restrict__ src4 =
        reinterpret_cast<const float4*>(hm + (size_t)plane * HWs);

    for (int i = t; i < NBIN; i += 256) hist[i] = 0;
    __syncthreads();

    auto hmax3 = [&](const float4& a) -> float4 {
        float vm1 = __shfl_up(a.w, 1, 32);
        float vp4 = __shfl_down(a.x, 1, 32);
        if (sx == 0) vm1 = a.x;            // SAME padding (self-dup neutral)
        if (sx == 31) vp4 = a.w;
        float4 h;
        h.x = fmaxf(fmaxf(vm1, a.x), a.y);
        h.y = fmaxf(fmaxf(a.x, a.y), a.z);
        h.z = fmaxf(fmaxf(a.y, a.z), a.w);
        h.w = fmaxf(fmaxf(a.z, a.w), vp4);
        return h;
    };

    unsigned* __restrict__ rb = rec + (size_t)plane * BCAP;
    int rbase = 0;                         // running block-slot base (all threads)

#pragma unroll
    for (int chunk = 0; chunk < 4; ++chunk) {
        const int y0 = band0 + (chunk << 2);

        // 6 independent loads (rows y0-1 .. y0+4, clamped at image boundary)
        float4 v[6];
#pragma unroll
        for (int r = 0; r < 6; ++r) {
            int rr = y0 - 1 + r;
            rr = rr < 0 ? 0 : (rr > 127 ? 127 : rr);
            v[r] = src4[(rr << 5) + sx];
        }

        unsigned pmask = 0;
        float4 hm1 = hmax3(v[0]);
        float4 h0  = hmax3(v[1]);
#pragma unroll
        for (int r = 0; r < 4; ++r) {
            float4 hp1 = hmax3(v[r + 2]);
            if (v[r + 1].x >= fmaxf(fmaxf(hm1.x, h0.x), hp1.x)) pmask |= 1u << (r * 4 + 0);
            if (v[r + 1].y >= fmaxf(fmaxf(hm1.y, h0.y), hp1.y)) pmask |= 1u << (r * 4 + 1);
            if (v[r + 1].z >= fmaxf(fmaxf(hm1.z, h0.z), hp1.z)) pmask |= 1u << (r * 4 + 2);
            if (v[r + 1].w >= fmaxf(fmaxf(hm1.w, h0.w), hp1.w)) pmask |= 1u << (r * 4 + 3);
            hm1 = h0; h0 = hp1;
        }

        // wave inclusive scan of per-thread peak counts
        int cntp = __popc(pmask);
        int sc = cntp;
#pragma unroll
        for (int off = 1; off < 64; off <<= 1) {
            int n = __shfl_up(sc, off, 64);
            if (lane >= off) sc += n;
        }
        if (lane == 63) wbase[wid] = sc;   // wave totals
        __syncthreads();
        int wexcl = 0;
#pragma unroll
        for (int i = 0; i < 4; ++i) if (i < wid) wexcl += wbase[i];
        const int blocktot = wbase[0] + wbase[1] + wbase[2] + wbase[3];
        int w = rbase + wexcl + sc - cntp; // deterministic offset in plane slot

#pragma unroll
        for (int r = 0; r < 4; ++r) {
            float vv0 = v[r + 1].x, vv1 = v[r + 1].y, vv2 = v[r + 1].z, vv3 = v[r + 1].w;
#pragma unroll
            for (int j = 0; j < 4; ++j) {
                if (pmask & (1u << (r * 4 + j))) {
                    float lv = (j == 0) ? vv0 : (j == 1) ? vv1 : (j == 2) ? vv2 : vv3;
                    unsigned bin = okey(lv) >> 21;
                    atomicAdd(&hist[bin], 1);
                    unsigned idx = ((unsigned)c << 14) | ((unsigned)(y0 + r) << 7)
                                 | (unsigned)(x0 + j);
                    if (w < BCAP) rb[w] = (bin << 21) | idx;
                    ++w;
                }
            }
        }
        __syncthreads();                   // protect wbase before next chunk
        rbase += blocktot;
    }

    if (t == 0) pbcnt[plane] = rbase > BCAP ? BCAP : rbase;

    for (int i = t; i < NBIN; i += 256) {
        int hv = hist[i];
        if (hv) atomicAdd(&bhist[b * NBIN + i], hv);   // fire-and-forget
    }
}

// One block per batch: cutoff = largest bin with suffix count >= K
// (superset of the exact sigmoid-top-100 incl. tie groups).
__global__ __launch_bounds__(256) void cut_kernel(const int* __restrict__ bhist,
                                                  int* __restrict__ cut) {
    __shared__ int csum[256];
    __shared__ int s_cut;
    const int b = blockIdx.x;
    const int t = threadIdx.x;

    int h[8]; int chunk = 0;
#pragma unroll
    for (int j = 0; j < 8; ++j) {
        h[j] = bhist[b * NBIN + (t << 3) + j];
        chunk += h[j];
    }
    csum[t] = chunk;
    if (t == 0) s_cut = 0;
    __syncthreads();
    for (int off = 1; off < 256; off <<= 1) {
        int v = (t + off < 256) ? csum[t + off] : 0;
        __syncthreads();
        csum[t] += v;
        __syncthreads();
    }
    if (csum[0] > KK) {
        int running = (t < 255) ? csum[t + 1] : 0;
        if (csum[t] >= KK && running < KK) {   // exactly one thread
            for (int j = 7; j >= 0; --j) {
                running += h[j];
                if (running >= KK) { s_cut = (t << 3) + j; break; }
            }
        }
    }
    __syncthreads();
    if (t == 0) cut[b] = s_cut;
}

// One block per plane slot: filter records against cut[b] -> survivor slot
// (LDS-atomic compaction only).
__global__ __launch_bounds__(256) void filter_kernel(const unsigned* __restrict__ rec,
                                                     const int* __restrict__ pbcnt,
                                                     const int* __restrict__ cut,
                                                     unsigned* __restrict__ surv,
                                                     int* __restrict__ pscnt) {
    __shared__ int s_n;
    const int bx = blockIdx.x;             // b*CC + c
    const int b = bx / CC;
    const int t = threadIdx.x;
    if (t == 0) s_n = 0;
    __syncthreads();

    int n = pbcnt[bx]; if (n > BCAP) n = BCAP;
    const int cutb = cut[b];
    const unsigned* __restrict__ rb = rec + (size_t)bx * BCAP;
    unsigned* __restrict__ sb = surv + (size_t)bx * SBCAP;
    for (int i = t; i < n; i += 256) {
        unsigned rv = rb[i];
        if ((int)(rv >> 21) >= cutb) {
            int sl = atomicAdd(&s_n, 1);   // LDS atomic: cheap
            if (sl < SBCAP) sb[sl] = rv & 0x1FFFFFu;
        }
    }
    __syncthreads();
    if (t == 0) pscnt[bx] = s_n > SBCAP ? SBCAP : s_n;
}

// One block per batch: gather survivors, exact logit -> sigmoid, sort by
// (sigmoid_bits desc, idx asc) == lax.top_k tie semantics, gather + emit.
__global__ __launch_bounds__(256) void topk_kernel(const unsigned* __restrict__ surv,
                                                   const int* __restrict__ pscnt,
                                                   const float* __restrict__ hm,
                                                   const float* __restrict__ bbox,
                                                   const float* __restrict__ offs,
                                                   const int* __restrict__ image_id,
                                                   float* __restrict__ out) {
    __shared__ int lcnt[CC];
    __shared__ unsigned uidx[2048];            // 8 KB
    __shared__ unsigned long long list[2048];  // 16 KB
    __shared__ int s_n;
    const int b = blockIdx.x;
    const int t = threadIdx.x;
    const float* __restrict__ hb = hm + (size_t)b * CC * HWs;

    if (t < CC) lcnt[t] = pscnt[b * CC + t];
    if (t == 0) s_n = 0;
    __syncthreads();

    for (int s = t; s < CC; s += 256) {
        int cs = lcnt[s]; if (cs > SBCAP) cs = SBCAP;
        if (cs) {
            int base = atomicAdd(&s_n, cs);
            const unsigned* __restrict__ sb = surv + ((size_t)b * CC + s) * SBCAP;
            for (int k = 0; k < cs; ++k)
                if (base + k < 2048) uidx[base + k] = sb[k];
        }
    }
    __syncthreads();
    int n = s_n; if (n > 2048) n = 2048;

    for (int i = t; i < n; i += 256) {
        unsigned idx = uidx[i];
        float lv = hb[idx];
        float s = 1.0f / (1.0f + expf(-lv));
        list[i] = ((unsigned long long)__float_as_uint(s) << 32) | (unsigned)(~idx);
    }
    int P = 128;
    while (P < n) P <<= 1;
    for (int i = n + t; i < P; i += 256) list[i] = 0ull;
    __syncthreads();

    for (int ksz = 2; ksz <= P; ksz <<= 1) {
        for (int j = ksz >> 1; j > 0; j >>= 1) {
            for (int i = t; i < P; i += 256) {
                int ixj = i ^ j;
                if (ixj > i) {
                    unsigned long long a = list[i], bb2 = list[ixj];
                    bool desc = ((i & ksz) == 0);
                    if (desc ? (a < bb2) : (a > bb2)) { list[i] = bb2; list[ixj] = a; }
                }
            }
            __syncthreads();
        }
    }

    if (t < KK) {
        float s = 0.0f; unsigned idx = 0;
        if (t < n) {
            unsigned long long cv = list[t];
            s = __uint_as_float((unsigned)(cv >> 32));
            idx = ~(unsigned)(cv & 0xFFFFFFFFu) & 0x1FFFFFu;
        }
        unsigned sp = idx & (HWs - 1);
        float cls = (float)(idx >> 14);
        float ysf = (float)(sp >> 7);
        float xsf = (float)(sp & 127);
        const float* __restrict__ ob  = offs + (size_t)b * 2 * HWs;
        const float* __restrict__ bbx = bbox + (size_t)b * 2 * HWs;
        float cx = xsf + ob[sp];
        float cy = ysf + ob[HWs + sp];
        float w = bbx[sp];
        float h = bbx[HWs + sp];
        float* row = out + ((size_t)b * KK + t) * 7;
        row[0] = (float)image_id[b];
        row[1] = (cx - w * 0.5f) * 4.0f;
        row[2] = (cy - h * 0.5f) * 4.0f;
        row[3] = (cx + w * 0.5f) * 4.0f;
        row[4] = (cy + h * 0.5f) * 4.0f;
        row[5] = s;
        row[6] = cls;
    }
}

extern "C" void kernel_launch(void* const* d_in, const int* in_sizes, int n_in,
                              void* d_out, int out_size, void* d_ws, size_t ws_size,
                              hipStream_t stream) {
    const float* hm      = (const float*)d_in[0];
    const float* bbox    = (const float*)d_in[1];
    const float* offset  = (const float*)d_in[2];
    const int*   img_id  = (const int*)d_in[3];
    float* out = (float*)d_out;

    char* ws = (char*)d_ws;
    int*      bhist = (int*)(ws + OFF_BHIST);
    int*      cut   = (int*)(ws + OFF_CUT);
    int*      pbcnt = (int*)(ws + OFF_PBCNT);
    int*      pscnt = (int*)(ws + OFF_PSCNT);
    unsigned* rec   = (unsigned*)(ws + OFF_REC);
    unsigned* surv  = (unsigned*)(ws + OFF_SURV);

    zero_hist_kernel<<<32, 256, 0, stream>>>((int4*)bhist);
    nms_kernel<<<BB * CC, 256, 0, stream>>>(hm, rec, pbcnt, bhist);
    cut_kernel<<<BB, 256, 0, stream>>>(bhist, cut);
    filter_kernel<<<BB * CC, 256, 0, stream>>>(rec, pbcnt, cut, surv, pscnt);
    topk_kernel<<<BB, 256, 0, stream>>>(surv, pscnt, hm, bbox, offset, img_id, out);
}